// Round 14
// baseline (389.091 us; speedup 1.0000x reference)
//
#include <hip/hip_runtime.h>
#include <hip/hip_bf16.h>
#include <stdint.h>

#define S_LEN 4096
#define DMODEL 512
#define NHEAD 8
#define DHEAD 64
#define NTOK 8192

typedef unsigned short ushort_t;
typedef __attribute__((ext_vector_type(8))) short short8;
typedef __attribute__((ext_vector_type(4))) float f32x4;
typedef unsigned long long u64;
typedef __attribute__((ext_vector_type(2))) unsigned uint2v;

__device__ __forceinline__ float bf2f(ushort_t h) {
    union { unsigned u; float f; } c; c.u = ((unsigned)h) << 16; return c.f;
}
__device__ __forceinline__ ushort_t f2bf(float f) {
    union { float f; unsigned u; } c; c.f = f;
    unsigned u = c.u + 0x7fffu + ((c.u >> 16) & 1u);
    return (ushort_t)(u >> 16);
}
// async global->LDS, 16B/lane; LDS dest MUST be a wave-uniform expression
// not derived from threadIdx (R10 lesson: wave-indexed LDS base -> ~27x stall).
__device__ __forceinline__ void glds16(const ushort_t* g, ushort_t* l) {
    __builtin_amdgcn_global_load_lds(
        (const __attribute__((address_space(1))) unsigned int*)g,
        (__attribute__((address_space(3))) unsigned int*)l, 16, 0, 0);
}

// ---------------- mask -> lane-transposed words (fused, one pass) ----------
// mbT[gq][kt][t*4+r]: u64 whose bit[lane] = mask[gq*16+(lane&15)][kt*32+t*16+(lane>>4)*4+r]
__global__ __launch_bounds__(256) void mask_prep(const int* __restrict__ mask,
        u64* __restrict__ mbT) {
    int gq = blockIdx.x;            // 0..255 (16-row groups)
    int ktg = blockIdx.y;           // 0..7
    int wv = threadIdx.x >> 6, lane = threadIdx.x & 63;
    int lr = lane & 15, lg = lane >> 4;
    const int* rowp = mask + (size_t)(gq * 16 + lr) * 4096;
#pragma unroll
    for (int j = 0; j < 4; j++) {
        int kt = ktg * 16 + wv * 4 + j;
        u64* outp = mbT + ((size_t)gq * 128 + kt) * 8;
#pragma unroll
        for (int t = 0; t < 2; t++)
#pragma unroll
            for (int r = 0; r < 4; r++) {
                int v = rowp[kt * 32 + t * 16 + lg * 4 + r];
                u64 bb = __ballot(v != 0);
                if (lane == t * 4 + r) outp[t * 4 + r] = bb;
            }
    }
}

// ---------------- all weight transposes in one launch ----------------
__global__ __launch_bounds__(256) void wtrans_all(const float* __restrict__ wq,
        const float* __restrict__ wk, const float* __restrict__ wv,
        const float* __restrict__ wo, const float* __restrict__ w1,
        const float* __restrict__ w2,
        ushort_t* wqT, ushort_t* wkT, ushort_t* wvT, ushort_t* woT,
        ushort_t* w1T, ushort_t* w2T) {
    __shared__ __attribute__((aligned(16))) ushort_t t[64][72];
    int z = blockIdx.z;
    const float* src; ushort_t* dst; int R, C;
    switch (z) {
        case 0: src = wq; dst = wqT; R = 512;  C = 512;  break;
        case 1: src = wk; dst = wkT; R = 512;  C = 512;  break;
        case 2: src = wv; dst = wvT; R = 512;  C = 512;  break;
        case 3: src = wo; dst = woT; R = 512;  C = 512;  break;
        case 4: src = w1; dst = w1T; R = 512;  C = 2048; break;
        default: src = w2; dst = w2T; R = 2048; C = 512; break;
    }
    int r0 = blockIdx.x * 64, c0 = blockIdx.y * 64;
    if (r0 >= R || c0 >= C) return;
    int tid = threadIdx.x;
    for (int i = tid; i < 4096; i += 256) {
        int r = i >> 6, c = i & 63;
        t[r][c] = f2bf(src[(size_t)(r0 + r) * C + c0 + c]);
    }
    __syncthreads();
    for (int i = tid; i < 512; i += 256) {
        int c = i >> 3, rb = i & 7;
        short8 vv;
#pragma unroll
        for (int j = 0; j < 8; j++) ((ushort_t*)&vv)[j] = t[rb * 8 + j][c];
        *(short8*)(dst + (size_t)(c0 + c) * R + r0 + rb * 8) = vv;
    }
}

// ---------------- LayerNorm: f32 in, bf16 out; 4 tokens/block ----------------
__global__ __launch_bounds__(256) void ln_f32(const float* __restrict__ x,
        const float* __restrict__ ga, const float* __restrict__ be,
        ushort_t* __restrict__ out) {
    int tok = blockIdx.x * 4 + (threadIdx.x >> 6);
    int lane = threadIdx.x & 63;
    const float* xr = x + (size_t)tok * DMODEL + lane * 8;
    f32x4 v0 = *(const f32x4*)xr;
    f32x4 v1 = *(const f32x4*)(xr + 4);
    float f[8];
    float s = 0.f, s2 = 0.f;
#pragma unroll
    for (int i = 0; i < 8; i++) {
        f[i] = (i < 4) ? v0[i] : v1[i - 4];
        s += f[i]; s2 += f[i] * f[i];
    }
#pragma unroll
    for (int off = 1; off < 64; off <<= 1) {
        s += __shfl_xor(s, off);
        s2 += __shfl_xor(s2, off);
    }
    float mean = s * (1.f / DMODEL);
    float var = (s2 - (float)DMODEL * mean * mean) * (1.f / (DMODEL - 1));
    var = fmaxf(var, 0.f);
    float inv = 1.f / (sqrtf(var) + 1e-6f);   // torch: eps added to std, ddof=1
    short8 o;
#pragma unroll
    for (int i = 0; i < 8; i++) {
        float val = ga[lane * 8 + i] * (f[i] - mean) * inv + be[lane * 8 + i];
        ((ushort_t*)&o)[i] = f2bf(val);
    }
    *(short8*)(out + (size_t)tok * DMODEL + lane * 8) = o;
}

// ---------------- LN2 + out-init fused: one x2f read -> h2 (bf16) + out=x2f+b2 ----
__global__ __launch_bounds__(256) void ln2_out(const float* __restrict__ x2f,
        const float* __restrict__ ga, const float* __restrict__ be,
        const float* __restrict__ b2, ushort_t* __restrict__ h2,
        float* __restrict__ out) {
    int tok = blockIdx.x * 4 + (threadIdx.x >> 6);
    int lane = threadIdx.x & 63;
    const float* xr = x2f + (size_t)tok * DMODEL + lane * 8;
    f32x4 v0 = *(const f32x4*)xr;
    f32x4 v1 = *(const f32x4*)(xr + 4);
    float f[8];
    float s = 0.f, s2 = 0.f;
#pragma unroll
    for (int i = 0; i < 8; i++) {
        f[i] = (i < 4) ? v0[i] : v1[i - 4];
        s += f[i]; s2 += f[i] * f[i];
    }
#pragma unroll
    for (int off = 1; off < 64; off <<= 1) {
        s += __shfl_xor(s, off);
        s2 += __shfl_xor(s2, off);
    }
    float mean = s * (1.f / DMODEL);
    float var = (s2 - (float)DMODEL * mean * mean) * (1.f / (DMODEL - 1));
    var = fmaxf(var, 0.f);
    float inv = 1.f / (sqrtf(var) + 1e-6f);
    short8 o;
    f32x4 ob0, ob1;
#pragma unroll
    for (int i = 0; i < 8; i++) {
        float val = ga[lane * 8 + i] * (f[i] - mean) * inv + be[lane * 8 + i];
        ((ushort_t*)&o)[i] = f2bf(val);
        float ov = f[i] + b2[lane * 8 + i];
        if (i < 4) ob0[i] = ov; else ob1[i - 4] = ov;
    }
    *(short8*)(h2 + (size_t)tok * DMODEL + lane * 8) = o;
    float* op = out + (size_t)tok * DMODEL + lane * 8;
    *(f32x4*)op = ob0;
    *(f32x4*)(op + 4) = ob1;
}

// ---------------- bf16 GEMM core, BK=64, single LDS buffer ----------------
// vtw: write C transposed per-head (V path): VT[((b*8+h)*64+d)*4096 + s]
template <int MW, int NW>
__device__ __forceinline__ void gemm_body(const ushort_t* __restrict__ A,
        const ushort_t* __restrict__ BT, void* __restrict__ C,
        int N, int Klen, int kstride, int kbeg, float scale,
        const float* __restrict__ bias, const float* __restrict__ res,
        int relu, int cf32, int atomicc, int vtw,
        ushort_t* As, ushort_t* Bs, int m0, int n0, int aoff, int coff) {
    int tid = threadIdx.x;
    int wave = tid >> 6, lane = tid & 63;
    int wm = wave >> 1, wn = wave & 1;
    int lr = lane & 15, lg = lane >> 4;
    int srow = lane >> 3, spos = lane & 7;
    int kst = (spos ^ srow) * 8;
    int rdk = lr & 7;
    f32x4 acc[MW][NW];
#pragma unroll
    for (int i = 0; i < MW; i++)
#pragma unroll
        for (int j = 0; j < NW; j++) acc[i][j] = (f32x4){0.f, 0.f, 0.f, 0.f};

    const ushort_t* Ag = A + (size_t)(m0 - aoff) * kstride + kbeg;
    const ushort_t* Bg = BT + (size_t)n0 * kstride + kbeg;

    for (int k0 = 0; k0 < Klen; k0 += 64) {
        __syncthreads();
        for (int ia = wave; ia < 4 * MW; ia += 4)
            glds16(Ag + (size_t)(ia * 8 + srow) * kstride + k0 + kst, As + ia * 8 * 64);
        for (int ib = wave; ib < 4 * NW; ib += 4)
            glds16(Bg + (size_t)(ib * 8 + srow) * kstride + k0 + kst, Bs + ib * 8 * 64);
        __syncthreads();
        short8 af[MW][2], bfv[NW][2];
#pragma unroll
        for (int t = 0; t < MW; t++) {
            const ushort_t* ar = As + (size_t)(wm * 16 * MW + t * 16 + lr) * 64;
            af[t][0] = *(const short8*)(ar + ((lg ^ rdk) * 8));
            af[t][1] = *(const short8*)(ar + (((lg + 4) ^ rdk) * 8));
        }
#pragma unroll
        for (int t = 0; t < NW; t++) {
            const ushort_t* br = Bs + (size_t)(wn * 16 * NW + t * 16 + lr) * 64;
            bfv[t][0] = *(const short8*)(br + ((lg ^ rdk) * 8));
            bfv[t][1] = *(const short8*)(br + (((lg + 4) ^ rdk) * 8));
        }
#pragma unroll
        for (int i = 0; i < MW; i++)
#pragma unroll
            for (int j = 0; j < NW; j++) {
                acc[i][j] = __builtin_amdgcn_mfma_f32_16x16x32_bf16(af[i][0], bfv[j][0], acc[i][j], 0, 0, 0);
                acc[i][j] = __builtin_amdgcn_mfma_f32_16x16x32_bf16(af[i][1], bfv[j][1], acc[i][j], 0, 0, 0);
            }
    }
    if (vtw) {
        // transposed per-head V write: 4 consecutive tokens -> one 8B store
#pragma unroll
        for (int i = 0; i < MW; i++) {
            int row = m0 + wm * 16 * MW + i * 16 + lg * 4;
            int bI = row >> 12, sI = row & 4095;
#pragma unroll
            for (int j = 0; j < NW; j++) {
                int col = n0 + wn * 16 * NW + j * 16 + lr;
                u64 pk = 0;
#pragma unroll
                for (int r = 0; r < 4; r++)
                    pk |= (u64)f2bf(acc[i][j][r] * scale) << (16 * r);
                *(u64*)((ushort_t*)C
                    + ((size_t)((bI * 8 + (col >> 6)) * 64 + (col & 63))) * 4096 + sI) = pk;
            }
        }
        return;
    }
#pragma unroll
    for (int i = 0; i < MW; i++) {
        int row = m0 + wm * 16 * MW + i * 16 + lg * 4;
#pragma unroll
        for (int j = 0; j < NW; j++) {
            int col = n0 + wn * 16 * NW + j * 16 + lr;
            float bb = bias ? bias[col] : 0.f;
#pragma unroll
            for (int r = 0; r < 4; r++) {
                float v = acc[i][j][r] * scale + bb;
                if (relu) v = fmaxf(v, 0.f);
                if (res) v += res[(size_t)(row + r) * N + col];
                size_t cidx = (size_t)(row + r - coff) * N + col;
                if (atomicc)   atomicAdd((float*)C + cidx, v);
                else if (cf32) ((float*)C)[cidx] = v;
                else           ((ushort_t*)C)[cidx] = f2bf(v);
            }
        }
    }
}

// ---------------- bf16 GEMM core, BK=64, DOUBLE-buffered (T3 2-phase) ----------
template <int MW, int NW>
__device__ __forceinline__ void gemm_body_db(const ushort_t* __restrict__ A,
        const ushort_t* __restrict__ BT, void* __restrict__ C,
        int N, int Klen, int kstride, int kbeg, float scale,
        const float* __restrict__ bias, const float* __restrict__ res,
        int relu, int cf32, int atomicc,
        ushort_t* As, ushort_t* Bs, int m0, int n0, int aoff, int coff) {
    int tid = threadIdx.x;
    int wave = tid >> 6, lane = tid & 63;
    int wm = wave >> 1, wn = wave & 1;
    int lr = lane & 15, lg = lane >> 4;
    int srow = lane >> 3, spos = lane & 7;
    int kst = (spos ^ srow) * 8;
    int rdk = lr & 7;
    f32x4 acc[MW][NW];
#pragma unroll
    for (int i = 0; i < MW; i++)
#pragma unroll
        for (int j = 0; j < NW; j++) acc[i][j] = (f32x4){0.f, 0.f, 0.f, 0.f};

    const ushort_t* Ag = A + (size_t)(m0 - aoff) * kstride + kbeg;
    const ushort_t* Bg = BT + (size_t)n0 * kstride + kbeg;
    const int ASZ = MW * 2048, BSZ = NW * 2048;   // elements per buffer

    // prologue: tile 0 into buf 0
    for (int ia = wave; ia < 4 * MW; ia += 4)
        glds16(Ag + (size_t)(ia * 8 + srow) * kstride + kst, As + ia * 8 * 64);
    for (int ib = wave; ib < 4 * NW; ib += 4)
        glds16(Bg + (size_t)(ib * 8 + srow) * kstride + kst, Bs + ib * 8 * 64);

    const int NT = Klen / 64;
#pragma unroll 1
    for (int t = 0; t < NT; t++) {
        int cur = t & 1;
        __builtin_amdgcn_s_barrier();   // all waves done computing buf cur^1
        if (t + 1 < NT) {
            int k0 = (t + 1) * 64;
            for (int ia = wave; ia < 4 * MW; ia += 4)
                glds16(Ag + (size_t)(ia * 8 + srow) * kstride + k0 + kst,
                       As + (cur ^ 1) * ASZ + ia * 8 * 64);
            for (int ib = wave; ib < 4 * NW; ib += 4)
                glds16(Bg + (size_t)(ib * 8 + srow) * kstride + k0 + kst,
                       Bs + (cur ^ 1) * BSZ + ib * 8 * 64);
            __builtin_amdgcn_s_waitcnt(3952 + MW + NW);  // vmcnt(MW+NW): tile t landed
        } else {
            __builtin_amdgcn_s_waitcnt(3952);            // vmcnt(0)
        }
        __builtin_amdgcn_s_barrier();   // partner waves' tile-t loads visible
        const ushort_t* Ab = As + cur * ASZ;
        const ushort_t* Bb = Bs + cur * BSZ;
        short8 af[MW][2], bfv[NW][2];
#pragma unroll
        for (int q = 0; q < MW; q++) {
            const ushort_t* ar = Ab + (size_t)(wm * 16 * MW + q * 16 + lr) * 64;
            af[q][0] = *(const short8*)(ar + ((lg ^ rdk) * 8));
            af[q][1] = *(const short8*)(ar + (((lg + 4) ^ rdk) * 8));
        }
#pragma unroll
        for (int q = 0; q < NW; q++) {
            const ushort_t* br = Bb + (size_t)(wn * 16 * NW + q * 16 + lr) * 64;
            bfv[q][0] = *(const short8*)(br + ((lg ^ rdk) * 8));
            bfv[q][1] = *(const short8*)(br + (((lg + 4) ^ rdk) * 8));
        }
#pragma unroll
        for (int i = 0; i < MW; i++)
#pragma unroll
            for (int j = 0; j < NW; j++) {
                acc[i][j] = __builtin_amdgcn_mfma_f32_16x16x32_bf16(af[i][0], bfv[j][0], acc[i][j], 0, 0, 0);
                acc[i][j] = __builtin_amdgcn_mfma_f32_16x16x32_bf16(af[i][1], bfv[j][1], acc[i][j], 0, 0, 0);
            }
    }
#pragma unroll
    for (int i = 0; i < MW; i++) {
        int row = m0 + wm * 16 * MW + i * 16 + lg * 4;
#pragma unroll
        for (int j = 0; j < NW; j++) {
            int col = n0 + wn * 16 * NW + j * 16 + lr;
            float bb = bias ? bias[col] : 0.f;
#pragma unroll
            for (int r = 0; r < 4; r++) {
                float v = acc[i][j][r] * scale + bb;
                if (relu) v = fmaxf(v, 0.f);
                if (res) v += res[(size_t)(row + r) * N + col];
                size_t cidx = (size_t)(row + r - coff) * N + col;
                if (atomicc)   atomicAdd((float*)C + cidx, v);
                else if (cf32) ((float*)C)[cidx] = v;
                else           ((ushort_t*)C)[cidx] = f2bf(v);
            }
        }
    }
}

__global__ __launch_bounds__(256) void gemm_bt64(const ushort_t* __restrict__ A,
        const ushort_t* __restrict__ BT, void* __restrict__ C,
        int N, int K, float scale, const float* bias, const float* res, int relu,
        int cf32, int m_base, int aoff, int coff) {
    __shared__ __attribute__((aligned(16))) ushort_t As[64 * 64];
    __shared__ __attribute__((aligned(16))) ushort_t Bs[64 * 64];
    gemm_body<2, 2>(A, BT, C, N, K, K, 0, scale, bias, res, relu, cf32, 0, 0, As, Bs,
                    m_base + blockIdx.x * 64, blockIdx.y * 64, aoff, coff);
}

// wo: 64x64 tile, double-buffered (1024 blocks = 4/CU)
__global__ __launch_bounds__(256) void gemm_bt64_db(const ushort_t* __restrict__ A,
        const ushort_t* __restrict__ BT, void* __restrict__ C,
        int N, int K, float scale, const float* bias, const float* res, int relu,
        int cf32, int m_base, int aoff, int coff) {
    __shared__ __attribute__((aligned(16))) ushort_t As[2 * 64 * 64];
    __shared__ __attribute__((aligned(16))) ushort_t Bs[2 * 64 * 64];
    gemm_body_db<2, 2>(A, BT, C, N, K, K, 0, scale, bias, res, relu, cf32, 0, As, Bs,
                       m_base + blockIdx.x * 64, blockIdx.y * 64, aoff, coff);
}

// w2 split-K x2, double-buffered: blockIdx.z = K-slice; atomicAdd into out
// (pre-initialized with x2f + b2 by ln2_out). Full M=8192 in one launch.
__global__ __launch_bounds__(256) void gemm_w2sk(const ushort_t* __restrict__ A,
        const ushort_t* __restrict__ BT, float* __restrict__ C,
        int m_base, int aoff) {
    __shared__ __attribute__((aligned(16))) ushort_t As[2 * 64 * 64];
    __shared__ __attribute__((aligned(16))) ushort_t Bs[2 * 64 * 64];
    int kbeg = blockIdx.z * 1024;
    gemm_body_db<2, 2>(A, BT, C, 512, 1024, 2048, kbeg, 1.f, nullptr, nullptr, 0, 1, 1,
                       As, Bs, m_base + blockIdx.x * 64, blockIdx.y * 64, aoff, 0);
}

// qkv: 128x128 tile; z==2 (V) writes VT[bh][d][s] directly (vtrans fused).
__global__ __launch_bounds__(256) void gemm_qkv(const ushort_t* __restrict__ A,
        const ushort_t* __restrict__ wqT, const ushort_t* __restrict__ wkT,
        const ushort_t* __restrict__ wvT,
        ushort_t* __restrict__ Q, ushort_t* __restrict__ Kb, ushort_t* __restrict__ VT) {
    __shared__ __attribute__((aligned(16))) ushort_t As[128 * 64];
    __shared__ __attribute__((aligned(16))) ushort_t Bs[128 * 64];
    int z = blockIdx.z;
    const ushort_t* W = (z == 0) ? wqT : ((z == 1) ? wkT : wvT);
    ushort_t* O = (z == 0) ? Q : ((z == 1) ? Kb : VT);
    // fold 1/sqrt(64) AND log2(e) into Q so attn can use raw v_exp_f32 (exp2)
    float sc = (z == 0) ? 0.18033688011112042f : 1.f;
    gemm_body<4, 4>(A, W, O, DMODEL, DMODEL, DMODEL, 0, sc, nullptr, nullptr, 0, 0, 0,
                    (z == 2) ? 1 : 0, As, Bs, blockIdx.x * 128, blockIdx.y * 128, 0, 0);
}

// ---------------- flash attention v9: R9 body + XCD-aware block swizzle ----
// 32 q/wave, 2 waves/block sharing K/V 2-deep dbuf LDS (16KB); in-register P
// transpose; denominator via ones-MFMA; SGPR-pair cndmask. NEW (T1): remap the
// flattened block id so each XCD gets a CONTIGUOUS 256-work-item chunk = 4
// (h,b,half) K/V panels = ~4MB, fitting its private 4MB L2. Without swizzle,
// qt-fastest linearization sprays the 64 blocks sharing one 1MB panel across
// all 8 XCDs -> each XCD streams all 32 panels (32MB >> L2) -> measured 74.5MB
// FETCH vs ~18MB unique. Attn is latency-bound: L2-hit (~200cy) vs HBM
// (~900cy) glds returns directly shrink exposed latency. Bijective: 2048%8==0.
__global__ __launch_bounds__(128, 4) void attn_kernel(const ushort_t* __restrict__ Q,
        const ushort_t* __restrict__ K, const ushort_t* __restrict__ VT,
        const u64* __restrict__ mbT, ushort_t* __restrict__ Opart,
        float* __restrict__ lpart) {
    __shared__ __attribute__((aligned(16))) ushort_t Ks[2][32 * 64];  // keys x d
    __shared__ __attribute__((aligned(16))) ushort_t Vs[2][64 * 32];  // d x keys
    // XCD swizzle: hw block bid -> work item (bid%8)*256 + bid/8
    int bid = blockIdx.x + 64 * blockIdx.y + 512 * blockIdx.z;   // 0..2047
    int wid = (bid & 7) * 256 + (bid >> 3);
    int qt = wid & 63, h = (wid >> 6) & 7, zz = wid >> 9;
    int b = zz >> 1, half = zz & 1;
    int tid = threadIdx.x;
    int wv = __builtin_amdgcn_readfirstlane(tid >> 6);   // SGPR wave id
    int lane = tid & 63;
    int lr = lane & 15, lg = lane >> 4;
    size_t tokbase = (size_t)b * S_LEN;
    int q0 = qt * 64 + wv * 32;
    int k0 = half * (S_LEN / 2);

    const ushort_t* Qp = Q + (tokbase + q0) * DMODEL + h * DHEAD;
    short8 qf[2][2];
#pragma unroll
    for (int u = 0; u < 2; u++) {
        qf[u][0] = *(const short8*)(Qp + (size_t)(u * 16 + lr) * DMODEL + lg * 8);
        qf[u][1] = *(const short8*)(Qp + (size_t)(u * 16 + lr) * DMODEL + 32 + lg * 8);
    }
    f32x4 o[2][4];
#pragma unroll
    for (int u = 0; u < 2; u++)
#pragma unroll
        for (int td = 0; td < 4; td++) o[u][td] = (f32x4){0.f, 0.f, 0.f, 0.f};
    f32x4 den[2] = {(f32x4){0.f, 0.f, 0.f, 0.f}, (f32x4){0.f, 0.f, 0.f, 0.f}};
    short8 ones8;
#pragma unroll
    for (int j = 0; j < 8; j++) ((ushort_t*)&ones8)[j] = 0x3F80;  // bf16 1.0

    int srow = lane >> 3, spos = lane & 7;      // K staging: 8 rows x 8 chunks
    int srow2 = lane >> 2, spos2 = lane & 3;    // V staging: 16 rows x 4 chunks
    int kst = (spos ^ srow) * 8;
    int vst = (spos2 ^ ((srow2 >> 1) & 3)) * 8;
    int rdk = lr & 7;
    int rdv = (lr >> 1) & 3;

    const ushort_t* kgl = K + (tokbase + k0) * DMODEL + h * DHEAD
                          + (size_t)srow * DMODEL + kst;
    const ushort_t* vgl = VT + (size_t)(b * NHEAD + h) * DHEAD * S_LEN
                          + (size_t)srow2 * S_LEN + k0 + vst;
    // wave-uniform mask-word base pointers (scalar-load path)
    const u64* mq0 = mbT + (((size_t)(q0 >> 4)) * 128 + half * 64) * 8;
    const u64* mq1 = mq0 + 128 * 8;

    // prologue: tile 0 into buf 0 (wave-split loads)
    if (wv == 0) {
        glds16(kgl + (size_t)0 * DMODEL, &Ks[0][0 * 64]);
        glds16(kgl + (size_t)8 * DMODEL, &Ks[0][8 * 64]);
        glds16(vgl + (size_t)0 * S_LEN, &Vs[0][0 * 32]);
        glds16(vgl + (size_t)16 * S_LEN, &Vs[0][16 * 32]);
    } else {
        glds16(kgl + (size_t)16 * DMODEL, &Ks[0][16 * 64]);
        glds16(kgl + (size_t)24 * DMODEL, &Ks[0][24 * 64]);
        glds16(vgl + (size_t)32 * S_LEN, &Vs[0][32 * 32]);
        glds16(vgl + (size_t)48 * S_LEN, &Vs[0][48 * 32]);
    }

    const int NIT = (S_LEN / 2) / 32;   // 64
#pragma unroll 1
    for (int kt = 0; kt < NIT; kt++) {
        int cur = kt & 1;
        // mask words for this tile: uniform address -> s_load; issue early
        const u64* m0 = mq0 + (size_t)kt * 8;
        const u64* m1 = mq1 + (size_t)kt * 8;
        __builtin_amdgcn_s_barrier();   // partner done reading buf cur^1 -> may overwrite
        if (kt + 1 < NIT) {
            const ushort_t* kgn = kgl + (size_t)(kt + 1) * 32 * DMODEL;
            const ushort_t* vgn = vgl + (kt + 1) * 32;
            if (wv == 0) {
                glds16(kgn + (size_t)0 * DMODEL, &Ks[cur ^ 1][0 * 64]);
                glds16(kgn + (size_t)8 * DMODEL, &Ks[cur ^ 1][8 * 64]);
                glds16(vgn + (size_t)0 * S_LEN, &Vs[cur ^ 1][0 * 32]);
                glds16(vgn + (size_t)16 * S_LEN, &Vs[cur ^ 1][16 * 32]);
            } else {
                glds16(kgn + (size_t)16 * DMODEL, &Ks[cur ^ 1][16 * 64]);
                glds16(kgn + (size_t)24 * DMODEL, &Ks[cur ^ 1][24 * 64]);
                glds16(vgn + (size_t)32 * S_LEN, &Vs[cur ^ 1][32 * 32]);
                glds16(vgn + (size_t)48 * S_LEN, &Vs[cur ^ 1][48 * 32]);
            }
            __builtin_amdgcn_s_waitcnt(3956);   // vmcnt(4): own tile-kt glds drained
        } else {
            __builtin_amdgcn_s_waitcnt(3952);   // vmcnt(0)
        }
        __builtin_amdgcn_s_barrier();   // partner's tile-kt loads visible in LDS
        const ushort_t* Kb_ = Ks[cur];
        const ushort_t* Vb_ = Vs[cur];
        // S^T = K Q^T : D[key][q]; col=q=u*16+lr, row=key=t*16+lg*4+r
        f32x4 s[2][2];
#pragma unroll
        for (int t = 0; t < 2; t++) {
            const ushort_t* kr = Kb_ + (t * 16 + lr) * 64;
            short8 kf0 = *(const short8*)(kr + ((lg ^ rdk) * 8));
            short8 kf1 = *(const short8*)(kr + (((lg + 4) ^ rdk) * 8));
#pragma unroll
            for (int u = 0; u < 2; u++) {
                f32x4 z = (f32x4){0.f, 0.f, 0.f, 0.f};
                z = __builtin_amdgcn_mfma_f32_16x16x32_bf16(kf0, qf[u][0], z, 0, 0, 0);
                z = __builtin_amdgcn_mfma_f32_16x16x32_bf16(kf1, qf[u][1], z, 0, 0, 0);
                s[t][u] = z;
            }
        }
        // exp2 (log2e folded into Q), mask via sgpr-pair cndmask
#pragma unroll
        for (int u = 0; u < 2; u++) {
            const u64* mu = u ? m1 : m0;
#pragma unroll
            for (int r = 0; r < 4; r++) {
                float p0, p1;
                asm("v_exp_f32 %0, %1\n\ts_nop 0" : "=v"(p0) : "v"(s[0][u][r]));
                asm("v_exp_f32 %0, %1\n\ts_nop 0" : "=v"(p1) : "v"(s[1][u][r]));
                asm("v_cndmask_b32 %0, 0, %1, %2" : "=v"(p0) : "v"(p0), "s"(mu[r]));
                asm("v_cndmask_b32 %0, 0, %1, %2" : "=v"(p1) : "v"(p1), "s"(mu[4 + r]));
                s[0][u][r] = p0; s[1][u][r] = p1;
            }
        }
        // V fragments (shared by both q-groups)
        short8 vf[4];
#pragma unroll
        for (int td = 0; td < 4; td++)
            vf[td] = *(const short8*)(Vb_ + (td * 16 + lr) * 32 + ((lg ^ rdv) * 8));
        // In-register P transpose: C-layout (4 keys @ lg*4, per t) ->
        // A-operand layout (8 keys @ g*8) via permlane32_swap + permlane16_swap.
#pragma unroll
        for (int u = 0; u < 2; u++) {
            unsigned c00, c01, c10, c11;
            asm("v_cvt_pk_bf16_f32 %0, %1, %2" : "=v"(c00) : "v"(s[0][u][0]), "v"(s[0][u][1]));
            asm("v_cvt_pk_bf16_f32 %0, %1, %2" : "=v"(c01) : "v"(s[0][u][2]), "v"(s[0][u][3]));
            asm("v_cvt_pk_bf16_f32 %0, %1, %2" : "=v"(c10) : "v"(s[1][u][0]), "v"(s[1][u][1]));
            asm("v_cvt_pk_bf16_f32 %0, %1, %2" : "=v"(c11) : "v"(s[1][u][2]), "v"(s[1][u][3]));
            auto r0 = __builtin_amdgcn_permlane32_swap(c00, c10, false, false);
            auto r1 = __builtin_amdgcn_permlane32_swap(c01, c11, false, false);
            auto p0 = __builtin_amdgcn_permlane16_swap(r0[0], r0[1], false, false);
            auto p1 = __builtin_amdgcn_permlane16_swap(r1[0], r1[1], false, false);
            union { unsigned u32[4]; short8 s8; } pk;
            pk.u32[0] = p0[0]; pk.u32[1] = p1[0]; pk.u32[2] = p0[1]; pk.u32[3] = p1[1];
            short8 pf = pk.s8;
            // O += P V ; den += P * ones (denominator in O-row layout)
#pragma unroll
            for (int td = 0; td < 4; td++)
                o[u][td] = __builtin_amdgcn_mfma_f32_16x16x32_bf16(pf, vf[td], o[u][td], 0, 0, 0);
            den[u] = __builtin_amdgcn_mfma_f32_16x16x32_bf16(pf, ones8, den[u], 0, 0, 0);
        }
    }
    // epilogue: store partial denom (row layout: q = u*16 + lg*4 + r, all 16
    // col-lanes hold copies -> store from lr==0) and unnormalized partial O.
    float* lp = lpart + (size_t)half * (NHEAD * 2 * S_LEN)
                + (size_t)(b * NHEAD + h) * S_LEN + q0;
    if (lr == 0) {
#pragma unroll
        for (int u = 0; u < 2; u++)
#pragma unroll
            for (int r = 0; r < 4; r++)
                lp[u * 16 + lg * 4 + r] = den[u][r];
    }
    ushort_t* Op = Opart + (size_t)half * NTOK * DMODEL;
#pragma unroll
    for (int u = 0; u < 2; u++) {
        size_t rowb = (tokbase + q0 + u * 16 + lg * 4) * DMODEL + h * DHEAD;
#pragma unroll
        for (int td = 0; td < 4; td++) {
            int cc = td * 16 + lr;
            Op[rowb + 0 * DMODEL + cc] = f2bf(o[u][td][0]);
            Op[rowb + 1 * DMODEL + cc] = f2bf(o[u][td][1]);
            Op[rowb + 2 * DMODEL + cc] = f2bf(o[u][td][2]);
            Op[rowb + 3 * DMODEL + cc] = f2bf(o[u][td][3]);
        }
    }
}

// ---------------- combine the two key-halves: ctx = (Oa+Ob)/(la+lb) ----------------
__global__ __launch_bounds__(256) void attn_combine(const ushort_t* __restrict__ Oa,
        const ushort_t* __restrict__ Ob, const float* __restrict__ la,
        const float* __restrict__ lb, ushort_t* __restrict__ ctx) {
    size_t idx = ((size_t)blockIdx.x * 256 + threadIdx.x) * 8;
    size_t tok = idx >> 9;
    int col = (int)(idx & 511);
    int h = col >> 6;
    int b = (int)(tok >> 12);
    int q = (int)(tok & 4095);
    size_t li = (size_t)(b * NHEAD + h) * S_LEN + q;
    float inv = 1.f / (la[li] + lb[li]);
    short8 va = *(const short8*)(Oa + idx);
    short8 vb = *(const short8*)(Ob + idx);
    short8 oo;
#pragma unroll
    for (int j = 0; j < 8; j++)
        ((ushort_t*)&oo)[j] = f2bf((bf2f(((const ushort_t*)&va)[j])
                                  + bf2f(((const ushort_t*)&vb)[j])) * inv);
    *(short8*)(ctx + idx) = oo;
}

extern "C" void kernel_launch(void* const* d_in, const int* in_sizes, int n_in,
                              void* d_out, int out_size, void* d_ws, size_t ws_size,
                              hipStream_t stream) {
    (void)in_sizes; (void)n_in; (void)out_size; (void)ws_size;
    const float* x    = (const float*)d_in[0];
    const int*   mask = (const int*)d_in[1];
    const float* w_q  = (const float*)d_in[2];
    const float* w_k  = (const float*)d_in[3];
    const float* w_v  = (const float*)d_in[4];
    const float* w_o  = (const float*)d_in[5];
    const float* w1   = (const float*)d_in[6];
    const float* b1   = (const float*)d_in[7];
    const float* w2   = (const float*)d_in[8];
    const float* b2   = (const float*)d_in[9];
    const float* l1a  = (const float*)d_in[10];
    const float* l1b  = (const float*)d_in[11];
    const float* l2a  = (const float*)d_in[12];
    const float* l2b  = (const float*)d_in[13];

    char* ws = (char*)d_ws;
    const size_t MB = 1024 * 1024;
    const size_t KB = 1024;
    // ---- workspace layout (<= 54 MB), phase-disjoint aliases ----
    // 0-2   w1T | 2-4 w2T | 4-4.5 wqT | 4.5-5 wkT | 5-5.5 wvT | 5.5-6 woT
    // 4-5   lpart (2x256KB) after qkv (over wqT/wkT, dead then)
    // 6-22  Opart 2x8MB (attn) -> ff1 low 16MB
    // 22-30 h (ln1 out, qkv A) -> ctx (combine out, wo A)
    // 30-38 Qb -> x2f low half; 30-38 also ff1 high after ln2_out (x2f dead)
    // 38-46 Kb -> x2f high half
    // 46-54 VTb (dead after attn) -> h2 (ln2 out, w1 A)
    // ff1 FULL 32MB = ws 6-38 (over Opart + x2f-low; both dead when w1 runs)
    // d_out: 0-2 mbT (dead after attn) -> out f32 16MB (ln2_out onwards)
    ushort_t* w1T  = (ushort_t*)(ws + 0);
    ushort_t* w2T  = (ushort_t*)(ws + 2 * MB);
    ushort_t* wqT  = (ushort_t*)(ws + 4 * MB);
    ushort_t* wkT  = (ushort_t*)(ws + 4 * MB + 512 * KB);
    ushort_t* wvT  = (ushort_t*)(ws + 5 * MB);
    ushort_t* woT  = (ushort_t*)(ws + 5 * MB + 512 * KB);
    float*    lpart = (float*)(ws + 4 * MB);
    ushort_t* Opart = (ushort_t*)(ws + 6 * MB);
    ushort_t* ff1  = (ushort_t*)(ws + 6 * MB);          // FULL 32MB (6-38)
    ushort_t* h    = (ushort_t*)(ws + 22 * MB);
    ushort_t* ctx  = (ushort_t*)(ws + 22 * MB);
    ushort_t* Qb   = (ushort_t*)(ws + 30 * MB);
    float*    x2f  = (float*)(ws + 30 * MB);
    ushort_t* Kb   = (ushort_t*)(ws + 38 * MB);
    ushort_t* VTb  = (ushort_t*)(ws + 46 * MB);
    ushort_t* h2   = (ushort_t*)(ws + 46 * MB);         // over dead VTb
    u64*      mbT  = (u64*)d_out;
    float*    out  = (float*)d_out;

    dim3 blk(256);
    mask_prep<<<dim3(256, 8), blk, 0, stream>>>(mask, mbT);
    wtrans_all<<<dim3(32, 32, 6), blk, 0, stream>>>(w_q, w_k, w_v, w_o, w1, w2,
            wqT, wkT, wvT, woT, w1T, w2T);
    ln_f32<<<dim3(NTOK / 4), blk, 0, stream>>>(x, l1a, l1b, h);
    gemm_qkv<<<dim3(64, 4, 3), blk, 0, stream>>>(h, wqT, wkT, wvT, Qb, Kb, VTb);
    attn_kernel<<<dim3(64, 8, 4), dim3(128), 0, stream>>>(Qb, Kb, VTb,
            mbT, Opart, lpart);
    attn_combine<<<dim3(2048), blk, 0, stream>>>(Opart,
            Opart + (size_t)NTOK * DMODEL, lpart, lpart + NHEAD * 2 * S_LEN, ctx);
    gemm_bt64_db<<<dim3(128, 8), blk, 0, stream>>>(ctx, woT, x2f, 512, 512, 1.f,
            nullptr, x, 0, 1, 0, 0, 0);
    ln2_out<<<dim3(NTOK / 4), blk, 0, stream>>>(x2f, l2a, l2b, b2, h2, out);
    // FFN un-chunked: full-M w1 (4096 blocks = 16/CU) then full-M split-K w2
    // (2048 blocks = 8/CU) — R11-proven high-TLP 64^2 configuration.
    gemm_bt64<<<dim3(128, 32), blk, 0, stream>>>(h2, w1T, ff1, 2048, 512, 1.f,
            b1, nullptr, 1, 0, 0, 0, 0);
    gemm_w2sk<<<dim3(128, 8, 2), blk, 0, stream>>>(ff1, w2T, out, 0, 0);
}

// Round 15
// 380.715 us; speedup vs baseline: 1.0220x; 1.0220x over previous
//
#include <hip/hip_runtime.h>
#include <hip/hip_bf16.h>
#include <stdint.h>

#define S_LEN 4096
#define DMODEL 512
#define NHEAD 8
#define DHEAD 64
#define NTOK 8192

typedef unsigned short ushort_t;
typedef __attribute__((ext_vector_type(8))) short short8;
typedef __attribute__((ext_vector_type(4))) float f32x4;
typedef unsigned long long u64;
typedef __attribute__((ext_vector_type(2))) unsigned uint2v;

__device__ __forceinline__ float bf2f(ushort_t h) {
    union { unsigned u; float f; } c; c.u = ((unsigned)h) << 16; return c.f;
}
__device__ __forceinline__ ushort_t f2bf(float f) {
    union { float f; unsigned u; } c; c.f = f;
    unsigned u = c.u + 0x7fffu + ((c.u >> 16) & 1u);
    return (ushort_t)(u >> 16);
}
// async global->LDS, 16B/lane; LDS dest MUST be a wave-uniform expression
// not derived from threadIdx (R10 lesson: wave-indexed LDS base -> ~27x stall).
__device__ __forceinline__ void glds16(const ushort_t* g, ushort_t* l) {
    __builtin_amdgcn_global_load_lds(
        (const __attribute__((address_space(1))) unsigned int*)g,
        (__attribute__((address_space(3))) unsigned int*)l, 16, 0, 0);
}

// ---------------- mask -> lane-transposed words (fused, one pass) ----------
// mbT[gq][kt][t*4+r]: u64 whose bit[lane] = mask[gq*16+(lane&15)][kt*32+t*16+(lane>>4)*4+r]
__global__ __launch_bounds__(256) void mask_prep(const int* __restrict__ mask,
        u64* __restrict__ mbT) {
    int gq = blockIdx.x;            // 0..255 (16-row groups)
    int ktg = blockIdx.y;           // 0..7
    int wv = threadIdx.x >> 6, lane = threadIdx.x & 63;
    int lr = lane & 15, lg = lane >> 4;
    const int* rowp = mask + (size_t)(gq * 16 + lr) * 4096;
#pragma unroll
    for (int j = 0; j < 4; j++) {
        int kt = ktg * 16 + wv * 4 + j;
        u64* outp = mbT + ((size_t)gq * 128 + kt) * 8;
#pragma unroll
        for (int t = 0; t < 2; t++)
#pragma unroll
            for (int r = 0; r < 4; r++) {
                int v = rowp[kt * 32 + t * 16 + lg * 4 + r];
                u64 bb = __ballot(v != 0);
                if (lane == t * 4 + r) outp[t * 4 + r] = bb;
            }
    }
}

// ---------------- all weight transposes in one launch ----------------
__global__ __launch_bounds__(256) void wtrans_all(const float* __restrict__ wq,
        const float* __restrict__ wk, const float* __restrict__ wv,
        const float* __restrict__ wo, const float* __restrict__ w1,
        const float* __restrict__ w2,
        ushort_t* wqT, ushort_t* wkT, ushort_t* wvT, ushort_t* woT,
        ushort_t* w1T, ushort_t* w2T) {
    __shared__ __attribute__((aligned(16))) ushort_t t[64][72];
    int z = blockIdx.z;
    const float* src; ushort_t* dst; int R, C;
    switch (z) {
        case 0: src = wq; dst = wqT; R = 512;  C = 512;  break;
        case 1: src = wk; dst = wkT; R = 512;  C = 512;  break;
        case 2: src = wv; dst = wvT; R = 512;  C = 512;  break;
        case 3: src = wo; dst = woT; R = 512;  C = 512;  break;
        case 4: src = w1; dst = w1T; R = 512;  C = 2048; break;
        default: src = w2; dst = w2T; R = 2048; C = 512; break;
    }
    int r0 = blockIdx.x * 64, c0 = blockIdx.y * 64;
    if (r0 >= R || c0 >= C) return;
    int tid = threadIdx.x;
    for (int i = tid; i < 4096; i += 256) {
        int r = i >> 6, c = i & 63;
        t[r][c] = f2bf(src[(size_t)(r0 + r) * C + c0 + c]);
    }
    __syncthreads();
    for (int i = tid; i < 512; i += 256) {
        int c = i >> 3, rb = i & 7;
        short8 vv;
#pragma unroll
        for (int j = 0; j < 8; j++) ((ushort_t*)&vv)[j] = t[rb * 8 + j][c];
        *(short8*)(dst + (size_t)(c0 + c) * R + r0 + rb * 8) = vv;
    }
}

// ---------------- LayerNorm: f32 in, bf16 out; 4 tokens/block ----------------
__global__ __launch_bounds__(256) void ln_f32(const float* __restrict__ x,
        const float* __restrict__ ga, const float* __restrict__ be,
        ushort_t* __restrict__ out) {
    int tok = blockIdx.x * 4 + (threadIdx.x >> 6);
    int lane = threadIdx.x & 63;
    const float* xr = x + (size_t)tok * DMODEL + lane * 8;
    f32x4 v0 = *(const f32x4*)xr;
    f32x4 v1 = *(const f32x4*)(xr + 4);
    float f[8];
    float s = 0.f, s2 = 0.f;
#pragma unroll
    for (int i = 0; i < 8; i++) {
        f[i] = (i < 4) ? v0[i] : v1[i - 4];
        s += f[i]; s2 += f[i] * f[i];
    }
#pragma unroll
    for (int off = 1; off < 64; off <<= 1) {
        s += __shfl_xor(s, off);
        s2 += __shfl_xor(s2, off);
    }
    float mean = s * (1.f / DMODEL);
    float var = (s2 - (float)DMODEL * mean * mean) * (1.f / (DMODEL - 1));
    var = fmaxf(var, 0.f);
    float inv = 1.f / (sqrtf(var) + 1e-6f);   // torch: eps added to std, ddof=1
    short8 o;
#pragma unroll
    for (int i = 0; i < 8; i++) {
        float val = ga[lane * 8 + i] * (f[i] - mean) * inv + be[lane * 8 + i];
        ((ushort_t*)&o)[i] = f2bf(val);
    }
    *(short8*)(out + (size_t)tok * DMODEL + lane * 8) = o;
}

// ---------------- LN2 + out-init fused: one x2f read -> h2 (bf16) + out=x2f+b2 ----
__global__ __launch_bounds__(256) void ln2_out(const float* __restrict__ x2f,
        const float* __restrict__ ga, const float* __restrict__ be,
        const float* __restrict__ b2, ushort_t* __restrict__ h2,
        float* __restrict__ out) {
    int tok = blockIdx.x * 4 + (threadIdx.x >> 6);
    int lane = threadIdx.x & 63;
    const float* xr = x2f + (size_t)tok * DMODEL + lane * 8;
    f32x4 v0 = *(const f32x4*)xr;
    f32x4 v1 = *(const f32x4*)(xr + 4);
    float f[8];
    float s = 0.f, s2 = 0.f;
#pragma unroll
    for (int i = 0; i < 8; i++) {
        f[i] = (i < 4) ? v0[i] : v1[i - 4];
        s += f[i]; s2 += f[i] * f[i];
    }
#pragma unroll
    for (int off = 1; off < 64; off <<= 1) {
        s += __shfl_xor(s, off);
        s2 += __shfl_xor(s2, off);
    }
    float mean = s * (1.f / DMODEL);
    float var = (s2 - (float)DMODEL * mean * mean) * (1.f / (DMODEL - 1));
    var = fmaxf(var, 0.f);
    float inv = 1.f / (sqrtf(var) + 1e-6f);
    short8 o;
    f32x4 ob0, ob1;
#pragma unroll
    for (int i = 0; i < 8; i++) {
        float val = ga[lane * 8 + i] * (f[i] - mean) * inv + be[lane * 8 + i];
        ((ushort_t*)&o)[i] = f2bf(val);
        float ov = f[i] + b2[lane * 8 + i];
        if (i < 4) ob0[i] = ov; else ob1[i - 4] = ov;
    }
    *(short8*)(h2 + (size_t)tok * DMODEL + lane * 8) = o;
    float* op = out + (size_t)tok * DMODEL + lane * 8;
    *(f32x4*)op = ob0;
    *(f32x4*)(op + 4) = ob1;
}

// ---------------- bf16 GEMM core, BK=64, single LDS buffer ----------------
// vtw: write C transposed per-head (V path): VT[((b*8+h)*64+d)*4096 + s]
template <int MW, int NW>
__device__ __forceinline__ void gemm_body(const ushort_t* __restrict__ A,
        const ushort_t* __restrict__ BT, void* __restrict__ C,
        int N, int Klen, int kstride, int kbeg, float scale,
        const float* __restrict__ bias, const float* __restrict__ res,
        int relu, int cf32, int atomicc, int vtw,
        ushort_t* As, ushort_t* Bs, int m0, int n0, int aoff, int coff) {
    int tid = threadIdx.x;
    int wave = tid >> 6, lane = tid & 63;
    int wm = wave >> 1, wn = wave & 1;
    int lr = lane & 15, lg = lane >> 4;
    int srow = lane >> 3, spos = lane & 7;
    int kst = (spos ^ srow) * 8;
    int rdk = lr & 7;
    f32x4 acc[MW][NW];
#pragma unroll
    for (int i = 0; i < MW; i++)
#pragma unroll
        for (int j = 0; j < NW; j++) acc[i][j] = (f32x4){0.f, 0.f, 0.f, 0.f};

    const ushort_t* Ag = A + (size_t)(m0 - aoff) * kstride + kbeg;
    const ushort_t* Bg = BT + (size_t)n0 * kstride + kbeg;

    for (int k0 = 0; k0 < Klen; k0 += 64) {
        __syncthreads();
        for (int ia = wave; ia < 4 * MW; ia += 4)
            glds16(Ag + (size_t)(ia * 8 + srow) * kstride + k0 + kst, As + ia * 8 * 64);
        for (int ib = wave; ib < 4 * NW; ib += 4)
            glds16(Bg + (size_t)(ib * 8 + srow) * kstride + k0 + kst, Bs + ib * 8 * 64);
        __syncthreads();
        short8 af[MW][2], bfv[NW][2];
#pragma unroll
        for (int t = 0; t < MW; t++) {
            const ushort_t* ar = As + (size_t)(wm * 16 * MW + t * 16 + lr) * 64;
            af[t][0] = *(const short8*)(ar + ((lg ^ rdk) * 8));
            af[t][1] = *(const short8*)(ar + (((lg + 4) ^ rdk) * 8));
        }
#pragma unroll
        for (int t = 0; t < NW; t++) {
            const ushort_t* br = Bs + (size_t)(wn * 16 * NW + t * 16 + lr) * 64;
            bfv[t][0] = *(const short8*)(br + ((lg ^ rdk) * 8));
            bfv[t][1] = *(const short8*)(br + (((lg + 4) ^ rdk) * 8));
        }
#pragma unroll
        for (int i = 0; i < MW; i++)
#pragma unroll
            for (int j = 0; j < NW; j++) {
                acc[i][j] = __builtin_amdgcn_mfma_f32_16x16x32_bf16(af[i][0], bfv[j][0], acc[i][j], 0, 0, 0);
                acc[i][j] = __builtin_amdgcn_mfma_f32_16x16x32_bf16(af[i][1], bfv[j][1], acc[i][j], 0, 0, 0);
            }
    }
    if (vtw) {
        // transposed per-head V write: 4 consecutive tokens -> one 8B store
#pragma unroll
        for (int i = 0; i < MW; i++) {
            int row = m0 + wm * 16 * MW + i * 16 + lg * 4;
            int bI = row >> 12, sI = row & 4095;
#pragma unroll
            for (int j = 0; j < NW; j++) {
                int col = n0 + wn * 16 * NW + j * 16 + lr;
                u64 pk = 0;
#pragma unroll
                for (int r = 0; r < 4; r++)
                    pk |= (u64)f2bf(acc[i][j][r] * scale) << (16 * r);
                *(u64*)((ushort_t*)C
                    + ((size_t)((bI * 8 + (col >> 6)) * 64 + (col & 63))) * 4096 + sI) = pk;
            }
        }
        return;
    }
#pragma unroll
    for (int i = 0; i < MW; i++) {
        int row = m0 + wm * 16 * MW + i * 16 + lg * 4;
#pragma unroll
        for (int j = 0; j < NW; j++) {
            int col = n0 + wn * 16 * NW + j * 16 + lr;
            float bb = bias ? bias[col] : 0.f;
#pragma unroll
            for (int r = 0; r < 4; r++) {
                float v = acc[i][j][r] * scale + bb;
                if (relu) v = fmaxf(v, 0.f);
                if (res) v += res[(size_t)(row + r) * N + col];
                size_t cidx = (size_t)(row + r - coff) * N + col;
                if (atomicc)   atomicAdd((float*)C + cidx, v);
                else if (cf32) ((float*)C)[cidx] = v;
                else           ((ushort_t*)C)[cidx] = f2bf(v);
            }
        }
    }
}

// ---------------- bf16 GEMM core, BK=64, DOUBLE-buffered (T3 2-phase) ----------
template <int MW, int NW>
__device__ __forceinline__ void gemm_body_db(const ushort_t* __restrict__ A,
        const ushort_t* __restrict__ BT, void* __restrict__ C,
        int N, int Klen, int kstride, int kbeg, float scale,
        const float* __restrict__ bias, const float* __restrict__ res,
        int relu, int cf32, int atomicc,
        ushort_t* As, ushort_t* Bs, int m0, int n0, int aoff, int coff) {
    int tid = threadIdx.x;
    int wave = tid >> 6, lane = tid & 63;
    int wm = wave >> 1, wn = wave & 1;
    int lr = lane & 15, lg = lane >> 4;
    int srow = lane >> 3, spos = lane & 7;
    int kst = (spos ^ srow) * 8;
    int rdk = lr & 7;
    f32x4 acc[MW][NW];
#pragma unroll
    for (int i = 0; i < MW; i++)
#pragma unroll
        for (int j = 0; j < NW; j++) acc[i][j] = (f32x4){0.f, 0.f, 0.f, 0.f};

    const ushort_t* Ag = A + (size_t)(m0 - aoff) * kstride + kbeg;
    const ushort_t* Bg = BT + (size_t)n0 * kstride + kbeg;
    const int ASZ = MW * 2048, BSZ = NW * 2048;   // elements per buffer

    // prologue: tile 0 into buf 0
    for (int ia = wave; ia < 4 * MW; ia += 4)
        glds16(Ag + (size_t)(ia * 8 + srow) * kstride + kst, As + ia * 8 * 64);
    for (int ib = wave; ib < 4 * NW; ib += 4)
        glds16(Bg + (size_t)(ib * 8 + srow) * kstride + kst, Bs + ib * 8 * 64);

    const int NT = Klen / 64;
#pragma unroll 1
    for (int t = 0; t < NT; t++) {
        int cur = t & 1;
        __builtin_amdgcn_s_barrier();   // all waves done computing buf cur^1
        if (t + 1 < NT) {
            int k0 = (t + 1) * 64;
            for (int ia = wave; ia < 4 * MW; ia += 4)
                glds16(Ag + (size_t)(ia * 8 + srow) * kstride + k0 + kst,
                       As + (cur ^ 1) * ASZ + ia * 8 * 64);
            for (int ib = wave; ib < 4 * NW; ib += 4)
                glds16(Bg + (size_t)(ib * 8 + srow) * kstride + k0 + kst,
                       Bs + (cur ^ 1) * BSZ + ib * 8 * 64);
            __builtin_amdgcn_s_waitcnt(3952 + MW + NW);  // vmcnt(MW+NW): tile t landed
        } else {
            __builtin_amdgcn_s_waitcnt(3952);            // vmcnt(0)
        }
        __builtin_amdgcn_s_barrier();   // partner waves' tile-t loads visible
        const ushort_t* Ab = As + cur * ASZ;
        const ushort_t* Bb = Bs + cur * BSZ;
        short8 af[MW][2], bfv[NW][2];
#pragma unroll
        for (int q = 0; q < MW; q++) {
            const ushort_t* ar = Ab + (size_t)(wm * 16 * MW + q * 16 + lr) * 64;
            af[q][0] = *(const short8*)(ar + ((lg ^ rdk) * 8));
            af[q][1] = *(const short8*)(ar + (((lg + 4) ^ rdk) * 8));
        }
#pragma unroll
        for (int q = 0; q < NW; q++) {
            const ushort_t* br = Bb + (size_t)(wn * 16 * NW + q * 16 + lr) * 64;
            bfv[q][0] = *(const short8*)(br + ((lg ^ rdk) * 8));
            bfv[q][1] = *(const short8*)(br + (((lg + 4) ^ rdk) * 8));
        }
#pragma unroll
        for (int i = 0; i < MW; i++)
#pragma unroll
            for (int j = 0; j < NW; j++) {
                acc[i][j] = __builtin_amdgcn_mfma_f32_16x16x32_bf16(af[i][0], bfv[j][0], acc[i][j], 0, 0, 0);
                acc[i][j] = __builtin_amdgcn_mfma_f32_16x16x32_bf16(af[i][1], bfv[j][1], acc[i][j], 0, 0, 0);
            }
    }
#pragma unroll
    for (int i = 0; i < MW; i++) {
        int row = m0 + wm * 16 * MW + i * 16 + lg * 4;
#pragma unroll
        for (int j = 0; j < NW; j++) {
            int col = n0 + wn * 16 * NW + j * 16 + lr;
            float bb = bias ? bias[col] : 0.f;
#pragma unroll
            for (int r = 0; r < 4; r++) {
                float v = acc[i][j][r] * scale + bb;
                if (relu) v = fmaxf(v, 0.f);
                if (res) v += res[(size_t)(row + r) * N + col];
                size_t cidx = (size_t)(row + r - coff) * N + col;
                if (atomicc)   atomicAdd((float*)C + cidx, v);
                else if (cf32) ((float*)C)[cidx] = v;
                else           ((ushort_t*)C)[cidx] = f2bf(v);
            }
        }
    }
}

__global__ __launch_bounds__(256) void gemm_bt64(const ushort_t* __restrict__ A,
        const ushort_t* __restrict__ BT, void* __restrict__ C,
        int N, int K, float scale, const float* bias, const float* res, int relu,
        int cf32, int m_base, int aoff, int coff) {
    __shared__ __attribute__((aligned(16))) ushort_t As[64 * 64];
    __shared__ __attribute__((aligned(16))) ushort_t Bs[64 * 64];
    gemm_body<2, 2>(A, BT, C, N, K, K, 0, scale, bias, res, relu, cf32, 0, 0, As, Bs,
                    m_base + blockIdx.x * 64, blockIdx.y * 64, aoff, coff);
}

// wo: 64x64 tile, double-buffered (1024 blocks = 4/CU)
__global__ __launch_bounds__(256) void gemm_bt64_db(const ushort_t* __restrict__ A,
        const ushort_t* __restrict__ BT, void* __restrict__ C,
        int N, int K, float scale, const float* bias, const float* res, int relu,
        int cf32, int m_base, int aoff, int coff) {
    __shared__ __attribute__((aligned(16))) ushort_t As[2 * 64 * 64];
    __shared__ __attribute__((aligned(16))) ushort_t Bs[2 * 64 * 64];
    gemm_body_db<2, 2>(A, BT, C, N, K, K, 0, scale, bias, res, relu, cf32, 0, As, Bs,
                       m_base + blockIdx.x * 64, blockIdx.y * 64, aoff, coff);
}

// w2 split-K x2, double-buffered: blockIdx.z = K-slice; atomicAdd into out
// (pre-initialized with x2f + b2 by ln2_out). Full M=8192 in one launch.
__global__ __launch_bounds__(256) void gemm_w2sk(const ushort_t* __restrict__ A,
        const ushort_t* __restrict__ BT, float* __restrict__ C,
        int m_base, int aoff) {
    __shared__ __attribute__((aligned(16))) ushort_t As[2 * 64 * 64];
    __shared__ __attribute__((aligned(16))) ushort_t Bs[2 * 64 * 64];
    int kbeg = blockIdx.z * 1024;
    gemm_body_db<2, 2>(A, BT, C, 512, 1024, 2048, kbeg, 1.f, nullptr, nullptr, 0, 1, 1,
                       As, Bs, m_base + blockIdx.x * 64, blockIdx.y * 64, aoff, 0);
}

// qkv: 128x128 tile; z==2 (V) writes VT[bh][d][s] directly (vtrans fused).
__global__ __launch_bounds__(256) void gemm_qkv(const ushort_t* __restrict__ A,
        const ushort_t* __restrict__ wqT, const ushort_t* __restrict__ wkT,
        const ushort_t* __restrict__ wvT,
        ushort_t* __restrict__ Q, ushort_t* __restrict__ Kb, ushort_t* __restrict__ VT) {
    __shared__ __attribute__((aligned(16))) ushort_t As[128 * 64];
    __shared__ __attribute__((aligned(16))) ushort_t Bs[128 * 64];
    int z = blockIdx.z;
    const ushort_t* W = (z == 0) ? wqT : ((z == 1) ? wkT : wvT);
    ushort_t* O = (z == 0) ? Q : ((z == 1) ? Kb : VT);
    // fold 1/sqrt(64) AND log2(e) into Q so attn can use raw v_exp_f32 (exp2)
    float sc = (z == 0) ? 0.18033688011112042f : 1.f;
    gemm_body<4, 4>(A, W, O, DMODEL, DMODEL, DMODEL, 0, sc, nullptr, nullptr, 0, 0, 0,
                    (z == 2) ? 1 : 0, As, Bs, blockIdx.x * 128, blockIdx.y * 128, 0, 0);
}

// ---------------- flash attention v9 (R14 champion): R9 body + XCD swizzle ----
// 32 q/wave, 2 waves/block sharing K/V 2-deep dbuf LDS (16KB); in-register P
// transpose; denominator via ones-MFMA; SGPR-pair cndmask. T1 swizzle: each
// XCD gets a contiguous 256-work-item chunk = 4 K/V panels (~4MB) fitting its
// private L2. MEASURED R14: FETCH 74.5 -> 24.6MB (3x), dur 95.5 -> 90.8us.
__global__ __launch_bounds__(128, 4) void attn_kernel(const ushort_t* __restrict__ Q,
        const ushort_t* __restrict__ K, const ushort_t* __restrict__ VT,
        const u64* __restrict__ mbT, ushort_t* __restrict__ Opart,
        float* __restrict__ lpart) {
    __shared__ __attribute__((aligned(16))) ushort_t Ks[2][32 * 64];  // keys x d
    __shared__ __attribute__((aligned(16))) ushort_t Vs[2][64 * 32];  // d x keys
    // XCD swizzle: hw block bid -> work item (bid%8)*256 + bid/8
    int bid = blockIdx.x + 64 * blockIdx.y + 512 * blockIdx.z;   // 0..2047
    int wid = (bid & 7) * 256 + (bid >> 3);
    int qt = wid & 63, h = (wid >> 6) & 7, zz = wid >> 9;
    int b = zz >> 1, half = zz & 1;
    int tid = threadIdx.x;
    int wv = __builtin_amdgcn_readfirstlane(tid >> 6);   // SGPR wave id
    int lane = tid & 63;
    int lr = lane & 15, lg = lane >> 4;
    size_t tokbase = (size_t)b * S_LEN;
    int q0 = qt * 64 + wv * 32;
    int k0 = half * (S_LEN / 2);

    const ushort_t* Qp = Q + (tokbase + q0) * DMODEL + h * DHEAD;
    short8 qf[2][2];
#pragma unroll
    for (int u = 0; u < 2; u++) {
        qf[u][0] = *(const short8*)(Qp + (size_t)(u * 16 + lr) * DMODEL + lg * 8);
        qf[u][1] = *(const short8*)(Qp + (size_t)(u * 16 + lr) * DMODEL + 32 + lg * 8);
    }
    f32x4 o[2][4];
#pragma unroll
    for (int u = 0; u < 2; u++)
#pragma unroll
        for (int td = 0; td < 4; td++) o[u][td] = (f32x4){0.f, 0.f, 0.f, 0.f};
    f32x4 den[2] = {(f32x4){0.f, 0.f, 0.f, 0.f}, (f32x4){0.f, 0.f, 0.f, 0.f}};
    short8 ones8;
#pragma unroll
    for (int j = 0; j < 8; j++) ((ushort_t*)&ones8)[j] = 0x3F80;  // bf16 1.0

    int srow = lane >> 3, spos = lane & 7;      // K staging: 8 rows x 8 chunks
    int srow2 = lane >> 2, spos2 = lane & 3;    // V staging: 16 rows x 4 chunks
    int kst = (spos ^ srow) * 8;
    int vst = (spos2 ^ ((srow2 >> 1) & 3)) * 8;
    int rdk = lr & 7;
    int rdv = (lr >> 1) & 3;

    const ushort_t* kgl = K + (tokbase + k0) * DMODEL + h * DHEAD
                          + (size_t)srow * DMODEL + kst;
    const ushort_t* vgl = VT + (size_t)(b * NHEAD + h) * DHEAD * S_LEN
                          + (size_t)srow2 * S_LEN + k0 + vst;
    // wave-uniform mask-word base pointers (scalar-load path)
    const u64* mq0 = mbT + (((size_t)(q0 >> 4)) * 128 + half * 64) * 8;
    const u64* mq1 = mq0 + 128 * 8;

    // prologue: tile 0 into buf 0 (wave-split loads)
    if (wv == 0) {
        glds16(kgl + (size_t)0 * DMODEL, &Ks[0][0 * 64]);
        glds16(kgl + (size_t)8 * DMODEL, &Ks[0][8 * 64]);
        glds16(vgl + (size_t)0 * S_LEN, &Vs[0][0 * 32]);
        glds16(vgl + (size_t)16 * S_LEN, &Vs[0][16 * 32]);
    } else {
        glds16(kgl + (size_t)16 * DMODEL, &Ks[0][16 * 64]);
        glds16(kgl + (size_t)24 * DMODEL, &Ks[0][24 * 64]);
        glds16(vgl + (size_t)32 * S_LEN, &Vs[0][32 * 32]);
        glds16(vgl + (size_t)48 * S_LEN, &Vs[0][48 * 32]);
    }

    const int NIT = (S_LEN / 2) / 32;   // 64
#pragma unroll 1
    for (int kt = 0; kt < NIT; kt++) {
        int cur = kt & 1;
        // mask words for this tile: uniform address -> s_load; issue early
        const u64* m0 = mq0 + (size_t)kt * 8;
        const u64* m1 = mq1 + (size_t)kt * 8;
        __builtin_amdgcn_s_barrier();   // partner done reading buf cur^1 -> may overwrite
        if (kt + 1 < NIT) {
            const ushort_t* kgn = kgl + (size_t)(kt + 1) * 32 * DMODEL;
            const ushort_t* vgn = vgl + (kt + 1) * 32;
            if (wv == 0) {
                glds16(kgn + (size_t)0 * DMODEL, &Ks[cur ^ 1][0 * 64]);
                glds16(kgn + (size_t)8 * DMODEL, &Ks[cur ^ 1][8 * 64]);
                glds16(vgn + (size_t)0 * S_LEN, &Vs[cur ^ 1][0 * 32]);
                glds16(vgn + (size_t)16 * S_LEN, &Vs[cur ^ 1][16 * 32]);
            } else {
                glds16(kgn + (size_t)16 * DMODEL, &Ks[cur ^ 1][16 * 64]);
                glds16(kgn + (size_t)24 * DMODEL, &Ks[cur ^ 1][24 * 64]);
                glds16(vgn + (size_t)32 * S_LEN, &Vs[cur ^ 1][32 * 32]);
                glds16(vgn + (size_t)48 * S_LEN, &Vs[cur ^ 1][48 * 32]);
            }
            __builtin_amdgcn_s_waitcnt(3956);   // vmcnt(4): own tile-kt glds drained
        } else {
            __builtin_amdgcn_s_waitcnt(3952);   // vmcnt(0)
        }
        __builtin_amdgcn_s_barrier();   // partner's tile-kt loads visible in LDS
        const ushort_t* Kb_ = Ks[cur];
        const ushort_t* Vb_ = Vs[cur];
        // S^T = K Q^T : D[key][q]; col=q=u*16+lr, row=key=t*16+lg*4+r
        f32x4 s[2][2];
#pragma unroll
        for (int t = 0; t < 2; t++) {
            const ushort_t* kr = Kb_ + (t * 16 + lr) * 64;
            short8 kf0 = *(const short8*)(kr + ((lg ^ rdk) * 8));
            short8 kf1 = *(const short8*)(kr + (((lg + 4) ^ rdk) * 8));
#pragma unroll
            for (int u = 0; u < 2; u++) {
                f32x4 z = (f32x4){0.f, 0.f, 0.f, 0.f};
                z = __builtin_amdgcn_mfma_f32_16x16x32_bf16(kf0, qf[u][0], z, 0, 0, 0);
                z = __builtin_amdgcn_mfma_f32_16x16x32_bf16(kf1, qf[u][1], z, 0, 0, 0);
                s[t][u] = z;
            }
        }
        // exp2 (log2e folded into Q), mask via sgpr-pair cndmask
#pragma unroll
        for (int u = 0; u < 2; u++) {
            const u64* mu = u ? m1 : m0;
#pragma unroll
            for (int r = 0; r < 4; r++) {
                float p0, p1;
                asm("v_exp_f32 %0, %1\n\ts_nop 0" : "=v"(p0) : "v"(s[0][u][r]));
                asm("v_exp_f32 %0, %1\n\ts_nop 0" : "=v"(p1) : "v"(s[1][u][r]));
                asm("v_cndmask_b32 %0, 0, %1, %2" : "=v"(p0) : "v"(p0), "s"(mu[r]));
                asm("v_cndmask_b32 %0, 0, %1, %2" : "=v"(p1) : "v"(p1), "s"(mu[4 + r]));
                s[0][u][r] = p0; s[1][u][r] = p1;
            }
        }
        // V fragments (shared by both q-groups)
        short8 vf[4];
#pragma unroll
        for (int td = 0; td < 4; td++)
            vf[td] = *(const short8*)(Vb_ + (td * 16 + lr) * 32 + ((lg ^ rdv) * 8));
        // In-register P transpose: C-layout (4 keys @ lg*4, per t) ->
        // A-operand layout (8 keys @ g*8) via permlane32_swap + permlane16_swap.
#pragma unroll
        for (int u = 0; u < 2; u++) {
            unsigned c00, c01, c10, c11;
            asm("v_cvt_pk_bf16_f32 %0, %1, %2" : "=v"(c00) : "v"(s[0][u][0]), "v"(s[0][u][1]));
            asm("v_cvt_pk_bf16_f32 %0, %1, %2" : "=v"(c01) : "v"(s[0][u][2]), "v"(s[0][u][3]));
            asm("v_cvt_pk_bf16_f32 %0, %1, %2" : "=v"(c10) : "v"(s[1][u][0]), "v"(s[1][u][1]));
            asm("v_cvt_pk_bf16_f32 %0, %1, %2" : "=v"(c11) : "v"(s[1][u][2]), "v"(s[1][u][3]));
            auto r0 = __builtin_amdgcn_permlane32_swap(c00, c10, false, false);
            auto r1 = __builtin_amdgcn_permlane32_swap(c01, c11, false, false);
            auto p0 = __builtin_amdgcn_permlane16_swap(r0[0], r0[1], false, false);
            auto p1 = __builtin_amdgcn_permlane16_swap(r1[0], r1[1], false, false);
            union { unsigned u32[4]; short8 s8; } pk;
            pk.u32[0] = p0[0]; pk.u32[1] = p1[0]; pk.u32[2] = p0[1]; pk.u32[3] = p1[1];
            short8 pf = pk.s8;
            // O += P V ; den += P * ones (denominator in O-row layout)
#pragma unroll
            for (int td = 0; td < 4; td++)
                o[u][td] = __builtin_amdgcn_mfma_f32_16x16x32_bf16(pf, vf[td], o[u][td], 0, 0, 0);
            den[u] = __builtin_amdgcn_mfma_f32_16x16x32_bf16(pf, ones8, den[u], 0, 0, 0);
        }
    }
    // epilogue: store partial denom (row layout: q = u*16 + lg*4 + r, all 16
    // col-lanes hold copies -> store from lr==0) and unnormalized partial O.
    float* lp = lpart + (size_t)half * (NHEAD * 2 * S_LEN)
                + (size_t)(b * NHEAD + h) * S_LEN + q0;
    if (lr == 0) {
#pragma unroll
        for (int u = 0; u < 2; u++)
#pragma unroll
            for (int r = 0; r < 4; r++)
                lp[u * 16 + lg * 4 + r] = den[u][r];
    }
    ushort_t* Op = Opart + (size_t)half * NTOK * DMODEL;
#pragma unroll
    for (int u = 0; u < 2; u++) {
        size_t rowb = (tokbase + q0 + u * 16 + lg * 4) * DMODEL + h * DHEAD;
#pragma unroll
        for (int td = 0; td < 4; td++) {
            int cc = td * 16 + lr;
            Op[rowb + 0 * DMODEL + cc] = f2bf(o[u][td][0]);
            Op[rowb + 1 * DMODEL + cc] = f2bf(o[u][td][1]);
            Op[rowb + 2 * DMODEL + cc] = f2bf(o[u][td][2]);
            Op[rowb + 3 * DMODEL + cc] = f2bf(o[u][td][3]);
        }
    }
}

// ---------------- combine the two key-halves: ctx = (Oa+Ob)/(la+lb) ----------------
__global__ __launch_bounds__(256) void attn_combine(const ushort_t* __restrict__ Oa,
        const ushort_t* __restrict__ Ob, const float* __restrict__ la,
        const float* __restrict__ lb, ushort_t* __restrict__ ctx) {
    size_t idx = ((size_t)blockIdx.x * 256 + threadIdx.x) * 8;
    size_t tok = idx >> 9;
    int col = (int)(idx & 511);
    int h = col >> 6;
    int b = (int)(tok >> 12);
    int q = (int)(tok & 4095);
    size_t li = (size_t)(b * NHEAD + h) * S_LEN + q;
    float inv = 1.f / (la[li] + lb[li]);
    short8 va = *(const short8*)(Oa + idx);
    short8 vb = *(const short8*)(Ob + idx);
    short8 oo;
#pragma unroll
    for (int j = 0; j < 8; j++)
        ((ushort_t*)&oo)[j] = f2bf((bf2f(((const ushort_t*)&va)[j])
                                  + bf2f(((const ushort_t*)&vb)[j])) * inv);
    *(short8*)(ctx + idx) = oo;
}

extern "C" void kernel_launch(void* const* d_in, const int* in_sizes, int n_in,
                              void* d_out, int out_size, void* d_ws, size_t ws_size,
                              hipStream_t stream) {
    (void)in_sizes; (void)n_in; (void)out_size; (void)ws_size;
    const float* x    = (const float*)d_in[0];
    const int*   mask = (const int*)d_in[1];
    const float* w_q  = (const float*)d_in[2];
    const float* w_k  = (const float*)d_in[3];
    const float* w_v  = (const float*)d_in[4];
    const float* w_o  = (const float*)d_in[5];
    const float* w1   = (const float*)d_in[6];
    const float* b1   = (const float*)d_in[7];
    const float* w2   = (const float*)d_in[8];
    const float* b2   = (const float*)d_in[9];
    const float* l1a  = (const float*)d_in[10];
    const float* l1b  = (const float*)d_in[11];
    const float* l2a  = (const float*)d_in[12];
    const float* l2b  = (const float*)d_in[13];

    char* ws = (char*)d_ws;
    const size_t MB = 1024 * 1024;
    const size_t KB = 1024;
    // ---- workspace layout (<= 54 MB), phase-disjoint aliases ----
    // 0-2   w1T | 2-4 w2T | 4-4.5 wqT | 4.5-5 wkT | 5-5.5 wvT | 5.5-6 woT
    // 4-5   lpart (2x256KB) after qkv (over wqT/wkT, dead then)
    // 6-22  Opart 2x8MB (attn) -> ff1 low 16MB
    // 22-30 h (ln1 out, qkv A) -> ctx (combine out, wo A)
    // 30-38 Qb -> x2f low half; 30-38 also ff1 high after ln2_out (x2f dead)
    // 38-46 Kb -> x2f high half
    // 46-54 VTb (dead after attn) -> h2 (ln2 out, w1 A)
    // ff1 FULL 32MB = ws 6-38 (over Opart + x2f-low; both dead when w1 runs)
    // d_out: 0-2 mbT (dead after attn) -> out f32 16MB (ln2_out onwards)
    ushort_t* w1T  = (ushort_t*)(ws + 0);
    ushort_t* w2T  = (ushort_t*)(ws + 2 * MB);
    ushort_t* wqT  = (ushort_t*)(ws + 4 * MB);
    ushort_t* wkT  = (ushort_t*)(ws + 4 * MB + 512 * KB);
    ushort_t* wvT  = (ushort_t*)(ws + 5 * MB);
    ushort_t* woT  = (ushort_t*)(ws + 5 * MB + 512 * KB);
    float*    lpart = (float*)(ws + 4 * MB);
    ushort_t* Opart = (ushort_t*)(ws + 6 * MB);
    ushort_t* ff1  = (ushort_t*)(ws + 6 * MB);          // FULL 32MB (6-38)
    ushort_t* h    = (ushort_t*)(ws + 22 * MB);
    ushort_t* ctx  = (ushort_t*)(ws + 22 * MB);
    ushort_t* Qb   = (ushort_t*)(ws + 30 * MB);
    float*    x2f  = (float*)(ws + 30 * MB);
    ushort_t* Kb   = (ushort_t*)(ws + 38 * MB);
    ushort_t* VTb  = (ushort_t*)(ws + 46 * MB);
    ushort_t* h2   = (ushort_t*)(ws + 46 * MB);         // over dead VTb
    u64*      mbT  = (u64*)d_out;
    float*    out  = (float*)d_out;

    dim3 blk(256);
    mask_prep<<<dim3(256, 8), blk, 0, stream>>>(mask, mbT);
    wtrans_all<<<dim3(32, 32, 6), blk, 0, stream>>>(w_q, w_k, w_v, w_o, w1, w2,
            wqT, wkT, wvT, woT, w1T, w2T);
    ln_f32<<<dim3(NTOK / 4), blk, 0, stream>>>(x, l1a, l1b, h);
    gemm_qkv<<<dim3(64, 4, 3), blk, 0, stream>>>(h, wqT, wkT, wvT, Qb, Kb, VTb);
    attn_kernel<<<dim3(64, 8, 4), dim3(128), 0, stream>>>(Qb, Kb, VTb,
            mbT, Opart, lpart);
    attn_combine<<<dim3(2048), blk, 0, stream>>>(Opart,
            Opart + (size_t)NTOK * DMODEL, lpart, lpart + NHEAD * 2 * S_LEN, ctx);
    gemm_bt64_db<<<dim3(128, 8), blk, 0, stream>>>(ctx, woT, x2f, 512, 512, 1.f,
            nullptr, x, 0, 1, 0, 0, 0);
    ln2_out<<<dim3(NTOK / 4), blk, 0, stream>>>(x2f, l2a, l2b, b2, h2, out);
    // FFN un-chunked: full-M w1 (4096 blocks = 16/CU) then full-M split-K w2
    // (2048 blocks = 8/CU) — R11-proven high-TLP 64^2 configuration.
    gemm_bt64<<<dim3(128, 32), blk, 0, stream>>>(h2, w1T, ff1, 2048, 512, 1.f,
            b1, nullptr, 1, 0, 0, 0, 0);
    gemm_w2sk<<<dim3(128, 8, 2), blk, 0, stream>>>(ff1, w2T, out, 0, 0);
}